// Round 5
// baseline (1153.916 us; speedup 1.0000x reference)
//
#include <hip/hip_runtime.h>
#include <math.h>

// ---------------------------------------------------------------------------
// VAE_Gumbel: B=4096, D=5000, H=512, Z=64
// Round 8: gemm_mfma staging via __builtin_amdgcn_global_load_lds width=16
//   (m97 structure: barrier -> async DMA -> barrier -> ds_read+MFMA).
//   LDS layout is linear in tid (wave-uniform base + lane*16B) so the DMA
//   dest constraint is satisfied; all global srcs 16B-aligned. Frees the
//   uint4 staging registers. topk kernel unchanged from R7 (131 us).
// out = [mu_x (4096x5000), mu_latent (4096x64), logvar_latent (4096x64)]
// ---------------------------------------------------------------------------

typedef __attribute__((ext_vector_type(8))) short bf16x8;
typedef __attribute__((ext_vector_type(4))) float f32x4;
typedef __attribute__((ext_vector_type(2))) float f32x2;

__device__ __forceinline__ short f2bf(float f) {  // RNE
    unsigned u = __builtin_bit_cast(unsigned, f);
    u += 0x7FFFu + ((u >> 16) & 1u);
    return (short)(u >> 16);
}
__device__ __forceinline__ float bf2f(short s) {
    unsigned u = ((unsigned)(unsigned short)s) << 16;
    return __builtin_bit_cast(float, u);
}

__device__ __forceinline__ float wave_max64(float v) {
#pragma unroll
    for (int off = 32; off > 0; off >>= 1) v = fmaxf(v, __shfl_xor(v, off, 64));
    return v;
}
__device__ __forceinline__ float wave_sum64(float v) {
#pragma unroll
    for (int off = 32; off > 0; off >>= 1) v += __shfl_xor(v, off, 64);
    return v;
}
__device__ __forceinline__ int wave_sum64_i(int v) {
#pragma unroll
    for (int off = 32; off > 0; off >>= 1) v += __shfl_xor(v, off, 64);
    return v;
}

// async global->LDS DMA, 16 B per lane (wave-uniform LDS base + lane*16)
__device__ __forceinline__ void async16(const short* g, short* l) {
    __builtin_amdgcn_global_load_lds(
        (const __attribute__((address_space(1))) unsigned*)g,
        (__attribute__((address_space(3))) unsigned*)l, 16, 0, 0);
}

// ======================= MFMA GEMM =========================================
// C[M,N] = A[M,Kp] @ Bt[Np,Kp]^T  (A, Bt bf16 row-major, contiguous Kp)
// 128x128 block tile, BK=32, 256 threads (4 waves, each 64x64).
// Staging: global_load_lds width=16 (async DMA), LDS linear in tid.
// SPLIT: A/B given as hi+lo bf16 pairs; acc = hi*hi + hi*lo + lo*hi.
// ATOMIC: split-K accumulation via atomicAdd (no bias/act).
// ACT: 0 none, 2 leaky, 3 sigmoid. GUMBEL: +log(-log(noise+1e-30)).
template <int SPLIT, int ACT, int GUMBEL, int ATOMIC, int OUT_BF16>
__global__ __launch_bounds__(256, 2) void gemm_mfma(
    const short* __restrict__ Ah, const short* __restrict__ Al,
    const short* __restrict__ Bth, const short* __restrict__ Btl,
    const float* __restrict__ bias, const float* __restrict__ noise,
    float* __restrict__ Cf, short* __restrict__ Cb, int N, int Kp)
{
    __shared__ short lds[(SPLIT ? 4 : 2) * 4096];  // As | Bs | (Asl | Bsl)
    short* As = lds;
    short* Bs = lds + 4096;

    const int tid = threadIdx.x;
    const int m0 = blockIdx.y << 7;
    const int n0 = blockIdx.x << 7;

    const int steps = Kp >> 5;
    const int per = (steps + gridDim.z - 1) / gridDim.z;
    const int s_begin = blockIdx.z * per;
    const int s_end = min(steps, s_begin + per);

    const int r = tid >> 2;
    const int p = tid & 3;
    const size_t a_off = (size_t)(m0 + r) * Kp + p * 8;
    const size_t b_off = (size_t)(n0 + r) * Kp + p * 8;
    const size_t row64 = (size_t)64 * Kp;
    short* As_d1 = As + tid * 8;
    short* As_d2 = As + (tid + 256) * 8;
    short* Bs_d1 = Bs + tid * 8;
    short* Bs_d2 = Bs + (tid + 256) * 8;

    const int lane = tid & 63;
    const int wid = tid >> 6;
    const int wm = (wid >> 1) << 6;
    const int wn = (wid & 1) << 6;
    const int fr = lane & 15;
    const int quad = lane >> 4;

    f32x4 acc[4][4];
#pragma unroll
    for (int i = 0; i < 4; i++)
#pragma unroll
        for (int j = 0; j < 4; j++)
            acc[i][j] = (f32x4){0.f, 0.f, 0.f, 0.f};

    for (int s = s_begin; s < s_end; s++) {
        const size_t k0 = (size_t)s << 5;
        __syncthreads();   // prev tile fully consumed before DMA overwrites
        async16(Ah + a_off + k0, As_d1);
        async16(Ah + a_off + row64 + k0, As_d2);
        async16(Bth + b_off + k0, Bs_d1);
        async16(Bth + b_off + row64 + k0, Bs_d2);
        if (SPLIT) {
            async16(Al + a_off + k0, As_d1 + 8192);
            async16(Al + a_off + row64 + k0, As_d2 + 8192);
            async16(Btl + b_off + k0, Bs_d1 + 8192);
            async16(Btl + b_off + row64 + k0, Bs_d2 + 8192);
        }
        __syncthreads();   // compiler emits vmcnt(0) drain before s_barrier

        bf16x8 af[4], bf[4];
#pragma unroll
        for (int i = 0; i < 4; i++)
            af[i] = *(const bf16x8*)(As + ((wm + i * 16 + fr) << 5) + (quad << 3));
#pragma unroll
        for (int j = 0; j < 4; j++)
            bf[j] = *(const bf16x8*)(Bs + ((wn + j * 16 + fr) << 5) + (quad << 3));
#pragma unroll
        for (int i = 0; i < 4; i++)
#pragma unroll
            for (int j = 0; j < 4; j++)
                acc[i][j] = __builtin_amdgcn_mfma_f32_16x16x32_bf16(af[i], bf[j], acc[i][j], 0, 0, 0);
        if (SPLIT) {
            bf16x8 al[4], bl[4];
#pragma unroll
            for (int i = 0; i < 4; i++)
                al[i] = *(const bf16x8*)(As + 8192 + ((wm + i * 16 + fr) << 5) + (quad << 3));
#pragma unroll
            for (int j = 0; j < 4; j++)
                bl[j] = *(const bf16x8*)(Bs + 8192 + ((wn + j * 16 + fr) << 5) + (quad << 3));
#pragma unroll
            for (int i = 0; i < 4; i++)
#pragma unroll
                for (int j = 0; j < 4; j++) {
                    acc[i][j] = __builtin_amdgcn_mfma_f32_16x16x32_bf16(af[i], bl[j], acc[i][j], 0, 0, 0);
                    acc[i][j] = __builtin_amdgcn_mfma_f32_16x16x32_bf16(al[i], bf[j], acc[i][j], 0, 0, 0);
                }
        }
    }

    // epilogue: D row = quad*4+rr, col = fr (m89/m91-verified layout)
#pragma unroll
    for (int i = 0; i < 4; i++) {
#pragma unroll
        for (int j = 0; j < 4; j++) {
#pragma unroll
            for (int rr = 0; rr < 4; rr++) {
                int gm = m0 + wm + i * 16 + quad * 4 + rr;
                int gn = n0 + wn + j * 16 + fr;
                if (gn < N) {
                    size_t o = (size_t)gm * N + gn;
                    float v = acc[i][j][rr];
                    if (ATOMIC) {
                        atomicAdd(Cf + o, v);
                    } else {
                        v += bias[gn];
                        if (GUMBEL) v += __logf(-__logf(noise[o] + 1e-30f));
                        if (ACT == 2) v = v > 0.f ? v : 0.01f * v;
                        if (ACT == 3) v = 1.f / (1.f + __expf(-v));
                        if (OUT_BF16) Cb[o] = f2bf(v); else Cf[o] = v;
                    }
                }
            }
        }
    }
}

// ======================= fp32 vector GEMM (small shapes) ===================
#define TILE 64
#define GBK  16
#define LDP  (TILE + 4)

template <int ACT, int OB>
__global__ __launch_bounds__(256) void gemm_f32(
    const float* __restrict__ A, const float* __restrict__ B,
    const float* __restrict__ bias, float* __restrict__ Cf, short* __restrict__ Cb,
    int M, int N, int K)
{
    __shared__ float As[GBK][LDP];
    __shared__ float Bs[GBK][LDP];
    const int tid = threadIdx.x;
    const int tx = tid & 15;
    const int ty = tid >> 4;
    const int m0 = blockIdx.y * TILE;
    const int n0 = blockIdx.x * TILE;

    float acc[4][4] = {};

    for (int k0 = 0; k0 < K; k0 += GBK) {
#pragma unroll
        for (int t = 0; t < 4; t++) {
            int idx = tid + t * 256;
            int ml = idx >> 4, kk = idx & 15;
            int gm = m0 + ml, gk = k0 + kk;
            As[kk][ml] = (gm < M && gk < K) ? A[(size_t)gm * K + gk] : 0.0f;
        }
#pragma unroll
        for (int t = 0; t < 4; t++) {
            int idx = tid + t * 256;
            int kb = idx >> 6, nl = idx & 63;
            int gk = k0 + kb, gn = n0 + nl;
            Bs[kb][nl] = (gk < K && gn < N) ? B[(size_t)gk * N + gn] : 0.0f;
        }
        __syncthreads();
#pragma unroll
        for (int kk = 0; kk < GBK; kk++) {
            float4 av = *(const float4*)&As[kk][ty * 4];
            float4 bv = *(const float4*)&Bs[kk][tx * 4];
            float a_[4] = {av.x, av.y, av.z, av.w};
            float b_[4] = {bv.x, bv.y, bv.z, bv.w};
#pragma unroll
            for (int i = 0; i < 4; i++)
#pragma unroll
                for (int j = 0; j < 4; j++)
                    acc[i][j] = fmaf(a_[i], b_[j], acc[i][j]);
        }
        __syncthreads();
    }

#pragma unroll
    for (int i = 0; i < 4; i++) {
        int gm = m0 + ty * 4 + i;
        if (gm >= M) continue;
#pragma unroll
        for (int j = 0; j < 4; j++) {
            int gn = n0 + tx * 4 + j;
            if (gn >= N) continue;
            float v = acc[i][j] + bias[gn];
            if (ACT == 2) v = (v > 0.0f) ? v : 0.01f * v;
            if (OB) Cb[(size_t)gm * N + gn] = f2bf(v);
            else    Cf[(size_t)gm * N + gn] = v;
        }
    }
}

// ======================= packs / BN / misc =================================
// A pack with split: fp32 [M,K] -> hi/lo bf16 [M,Kp], 4 elems/thread
__global__ __launch_bounds__(256) void pack_a_split(
    const float* __restrict__ in, short* __restrict__ hi, short* __restrict__ lo,
    int K, int Kp)
{
    int k4 = (blockIdx.x * 256 + threadIdx.x) * 4;
    if (k4 >= Kp) return;
    int m = blockIdx.y;
    float v[4] = {0.f, 0.f, 0.f, 0.f};
    if (k4 + 3 < K) {
        float4 f = *(const float4*)(in + (size_t)m * K + k4);
        v[0] = f.x; v[1] = f.y; v[2] = f.z; v[3] = f.w;
    } else {
#pragma unroll
        for (int j = 0; j < 4; j++)
            if (k4 + j < K) v[j] = in[(size_t)m * K + k4 + j];
    }
    unsigned hp[2], lp[2];
#pragma unroll
    for (int j = 0; j < 2; j++) {
        short h0 = f2bf(v[2 * j]), h1 = f2bf(v[2 * j + 1]);
        short l0 = f2bf(v[2 * j] - bf2f(h0)), l1 = f2bf(v[2 * j + 1] - bf2f(h1));
        hp[j] = (unsigned)(unsigned short)h0 | ((unsigned)(unsigned short)h1 << 16);
        lp[j] = (unsigned)(unsigned short)l0 | ((unsigned)(unsigned short)l1 << 16);
    }
    size_t o = (size_t)m * Kp + k4;
    *(uint2*)(hi + o) = *(uint2*)hp;
    *(uint2*)(lo + o) = *(uint2*)lp;
}

// B^T pack: in fp32 [K,N] -> bf16 [Np,Kp] transposed (zero pad)
template <int SPLITB>
__global__ __launch_bounds__(1024) void pack_bt(
    const float* __restrict__ B, short* __restrict__ bth, short* __restrict__ btl,
    int K, int N, int Kp, int Np)
{
    __shared__ float t[32][33];
    int k0 = blockIdx.x * 32, n0 = blockIdx.y * 32;
    int tx = threadIdx.x, ty = threadIdx.y;
    int gk = k0 + ty, gn = n0 + tx;
    t[ty][tx] = (gk < K && gn < N) ? B[(size_t)gk * N + gn] : 0.f;
    __syncthreads();
    int on = n0 + ty, ok = k0 + tx;
    if (on < Np && ok < Kp) {
        float v = t[tx][ty];
        short h = f2bf(v);
        size_t o = (size_t)on * Kp + ok;
        bth[o] = h;
        if (SPLITB) btl[o] = f2bf(v - bf2f(h));
    }
}

__global__ __launch_bounds__(256) void bn_stats_kernel(
    const float* __restrict__ h, float* __restrict__ csum, float* __restrict__ csq)
{
    int c = threadIdx.x;
    int r0 = blockIdx.x * 32;
    float s0 = 0, q0 = 0, s1 = 0, q1 = 0;
    for (int r = 0; r < 32; r++) {
        const float* row = h + (size_t)(r0 + r) * 512;
        float a = row[c], b = row[c + 256];
        s0 += a; q0 = fmaf(a, a, q0);
        s1 += b; q1 = fmaf(b, b, q1);
    }
    atomicAdd(&csum[c], s0);       atomicAdd(&csq[c], q0);
    atomicAdd(&csum[c + 256], s1); atomicAdd(&csq[c + 256], q1);
}

__global__ __launch_bounds__(256) void bn_apply_split(
    const float* __restrict__ h, const float* __restrict__ csum, const float* __restrict__ csq,
    const float* __restrict__ g, const float* __restrict__ b,
    short* __restrict__ hh, short* __restrict__ hl)
{
    int idx = blockIdx.x * 256 + threadIdx.x;
    int c = idx & 511;
    float mean = csum[c] * (1.0f / 4096.0f);
    float var  = csq[c] * (1.0f / 4096.0f) - mean * mean;
    float inv  = rsqrtf(var + 1e-5f);
    float v = (h[idx] - mean) * inv * g[c] + b[c];
    v = fmaxf(v, 0.0f);
    short hi = f2bf(v);
    hh[idx] = hi;
    hl[idx] = f2bf(v - bf2f(hi));
}

template <int OB>
__global__ __launch_bounds__(256) void bias_act(
    const float* __restrict__ in, const float* __restrict__ bias,
    float* __restrict__ outf, short* __restrict__ outb, int mask, int total)
{
    int i = blockIdx.x * 256 + threadIdx.x;
    if (i < total) {
        float v = in[i] + bias[i & mask];
        v = v > 0.f ? v : 0.01f * v;
        if (OB) outb[i] = f2bf(v); else outf[i] = v;
    }
}

__global__ void zero_kernel(float* p, int n) {
    int i = blockIdx.x * 256 + threadIdx.x;
    if (i < n) p[i] = 0.0f;
}

// ---- continuous top-k (K=50, T=0.1), active-set compaction ----------------
// (unchanged from R7: 131 us, verified)
#define CMAX 2048

__global__ __launch_bounds__(256) void topk_xm_kernel(
    const float* __restrict__ wsrc, const float* __restrict__ x,
    short* __restrict__ xm, int N)   // N even, N <= 5024
{
    __shared__ float tc[CMAX];
    __shared__ unsigned short ic[CMAX];
    __shared__ float redmx[4];
    __shared__ float redsum[4];
    __shared__ int   redcnt[4];
    __shared__ float redsi[4];
    __shared__ float red[2][4];
    __shared__ int cnt_sh;

    const int row = blockIdx.x;
    const int tid = threadIdx.x;
    const int lane = tid & 63;
    const int wid = tid >> 6;
    const float* wr = wsrc + (size_t)row * N;
    const float* xr = x + (size_t)row * N;
    short* xmr = xm + (size_t)row * 5024;

    if (tid == 0) cnt_sh = 0;

    // ---- load w (pairs), block max C ----
    f32x2 w[10];
    float lm = -3.0e38f;
#pragma unroll
    for (int i = 0; i < 10; i++) {
        int e0 = (tid + (i << 8)) << 1;
        f32x2 v;
        if (e0 < N) v = *(const f32x2*)(wr + e0);
        else        v = (f32x2){-3.0e38f, -3.0e38f};
        w[i] = v;
        lm = fmaxf(lm, fmaxf(v[0], v[1]));
    }
    lm = wave_max64(lm);
    if (lane == 0) redmx[wid] = lm;
    __syncthreads();
    const float C = fmaxf(fmaxf(redmx[0], redmx[1]), fmaxf(redmx[2], redmx[3]));

    // ---- t init + s0 ----
    f32x2 t2[10];
    float ls = 0.0f;
#pragma unroll
    for (int i = 0; i < 10; i++) {
        int e0 = (tid + (i << 8)) << 1;
        f32x2 ti;
        if (e0 < N) {
            ti[0] = __expf((w[i][0] - C) * 10.0f);
            ti[1] = __expf((w[i][1] - C) * 10.0f);
        } else {
            ti = (f32x2){0.f, 0.f};
        }
        t2[i] = ti;
        ls += ti[0] + ti[1];
    }
    ls = wave_sum64(ls);
    if (lane == 0) redsum[wid] = ls;
    __syncthreads();
    const float s0 = redsum[0] + redsum[1] + redsum[2] + redsum[3];

    // ---- adaptive threshold: counts at th1, th2 (packed int reduce) ----
    const float th1 = 1e-8f * s0, th2 = 1e-7f * s0;
    int cpk = 0;
#pragma unroll
    for (int i = 0; i < 10; i++) {
#pragma unroll
        for (int h = 0; h < 2; h++) {
            float tv = t2[i][h];
            cpk += (tv > th1 ? 1 : 0) + (tv > th2 ? (1 << 16) : 0);
        }
    }
    cpk = wave_sum64_i(cpk);
    if (lane == 0) redcnt[wid] = cpk;
    __syncthreads();
    int ctot = redcnt[0] + redcnt[1] + redcnt[2] + redcnt[3];
    const int c1 = ctot & 0xFFFF;
    const float TH = (c1 <= CMAX) ? th1 : th2;

    // ---- s_inact = sum of inactive t ----
    float si = 0.0f;
#pragma unroll
    for (int i = 0; i < 10; i++) {
#pragma unroll
        for (int h = 0; h < 2; h++) {
            float tv = t2[i][h];
            si += (tv > TH) ? 0.0f : tv;
        }
    }
    si = wave_sum64(si);
    if (lane == 0) redsi[wid] = si;
    __syncthreads();
    const float s_inact = redsi[0] + redsi[1] + redsi[2] + redsi[3];

    // ---- compaction: ballot + mbcnt prefix within wave, LDS atomic base ----
#pragma unroll
    for (int i = 0; i < 10; i++) {
#pragma unroll
        for (int h = 0; h < 2; h++) {
            float tv = t2[i][h];
            bool act = tv > TH;
            unsigned long long mk = __ballot(act);
            int wb = 0;
            if (lane == 0) wb = atomicAdd(&cnt_sh, (int)__popcll(mk));
            wb = __shfl(wb, 0);
            if (act) {
                int pos = wb + (int)__builtin_amdgcn_mbcnt_hi(
                    (unsigned)(mk >> 32),
                    __builtin_amdgcn_mbcnt_lo((unsigned)mk, 0u));
                if (pos < CMAX) {
                    tc[pos] = tv;
                    ic[pos] = (unsigned short)(((tid + (i << 8)) << 1) + h);
                }
            }
        }
    }
    __syncthreads();
    const int cnt = min(cnt_sh, CMAX);

    // ---- gather candidates into 8 register slots (4 pairs) ----
    f32x2 tr[4], sr[4];
#pragma unroll
    for (int kk = 0; kk < 4; kk++) {
        int s_lo = tid + ((kk * 2) << 8);
        int s_hi = tid + ((kk * 2 + 1) << 8);
        tr[kk][0] = (s_lo < cnt) ? tc[s_lo] : 0.0f;
        tr[kk][1] = (s_hi < cnt) ? tc[s_hi] : 0.0f;
        sr[kk] = (f32x2){0.f, 0.f};
    }

    // ---- 50-iteration recurrence on the active set ----
    float s = s0;
    for (int it = 0; it < 50; it++) {
        const float rs = 1.0f / s;
        const f32x2 rs2 = {rs, rs};
        f32x2 nls2 = {0.f, 0.f};
#pragma unroll
        for (int kk = 0; kk < 4; kk++) {
            f32x2 ti = tr[kk];
            f32x2 oh = ti * rs2;
            sr[kk] += oh;
            f32x2 m = (f32x2){1.f, 1.f} - oh;
            f32x2 m2 = m * m;
            f32x2 m4 = m2 * m2;
            f32x2 m8 = m4 * m4;
            ti *= m8 * m2;          // * (1-oh)^10
            tr[kk] = ti;
            nls2 += ti;
        }
        float nls = wave_sum64(nls2[0] + nls2[1]);
        int buf = (it + 1) & 1;
        if (lane == 0) red[buf][wid] = nls;
        __syncthreads();
        s = fmaxf(red[buf][0] + red[buf][1] + red[buf][2] + red[buf][3] + s_inact,
                  1e-30f);
    }

    // ---- zero-fill xm row (incl. pad), then scatter candidates ----
#pragma unroll
    for (int i = 0; i < 10; i++) {
        int e0 = (tid + (i << 8)) << 1;
        if (e0 < 5024) *(unsigned*)(xmr + e0) = 0u;
    }
    __syncthreads();
#pragma unroll
    for (int k = 0; k < 8; k++) {
        int slot = tid + (k << 8);
        if (slot < cnt) {
            int idx = ic[slot];
            float sv = sr[k >> 1][k & 1];
            xmr[idx] = f2bf(xr[idx] * sv);
        }
    }
}

__global__ void reparam_kernel(const float* __restrict__ mu, const float* __restrict__ lv,
                               const float* __restrict__ eps, float* __restrict__ z, int n)
{
    int i = blockIdx.x * 256 + threadIdx.x;
    if (i < n) z[i] = fmaf(eps[i], expf(0.5f * lv[i]), mu[i]);
}

// ---------------------------------------------------------------------------
extern "C" void kernel_launch(void* const* d_in, const int* in_sizes, int n_in,
                              void* d_out, int out_size, void* d_ws, size_t ws_size,
                              hipStream_t stream)
{
    const float* x      = (const float*)d_in[0];
    const float* noise  = (const float*)d_in[1];
    const float* epsv   = (const float*)d_in[2];
    const float* wc_w1  = (const float*)d_in[3];
    const float* bn_g   = (const float*)d_in[5];
    const float* bn_b   = (const float*)d_in[6];
    const float* wc_w2  = (const float*)d_in[7];
    const float* wc_b2  = (const float*)d_in[8];
    const float* enc_w1 = (const float*)d_in[9];
    const float* enc_b1 = (const float*)d_in[10];
    const float* enc_w2 = (const float*)d_in[11];
    const float* enc_b2 = (const float*)d_in[12];
    const float* enc_w3 = (const float*)d_in[13];
    const float* enc_b3 = (const float*)d_in[14];
    const float* enc_w4 = (const float*)d_in[15];
    const float* enc_b4 = (const float*)d_in[16];
    const float* mean_w = (const float*)d_in[17];
    const float* mean_b = (const float*)d_in[18];
    const float* lv_w   = (const float*)d_in[19];
    const float* lv_b   = (const float*)d_in[20];
    const float* dec_w1 = (const float*)d_in[21];
    const float* dec_b1 = (const float*)d_in[22];
    const float* dec_w2 = (const float*)d_in[23];
    const float* dec_b2 = (const float*)d_in[24];

    const int B = 4096, D = 5000, H = 512, Z = 64;
    const int Dk = 5024;   // D padded to 32 (K pad)
    const int Dn = 5120;   // D padded to 128 (N pad for Bt rows)

    float* out  = (float*)d_out;
    float* mu_x = out;                        // also holds w until topk
    float* mu_l = out + (size_t)B * D;
    float* lv_l = mu_l + (size_t)B * Z;
    float* w_buf = mu_x;

    char* base = (char*)d_ws;
    size_t off = 0;
    auto alloc = [&](size_t bytes) { size_t r = off; off += (bytes + 255) & ~(size_t)255; return r; };
    const size_t XS = (size_t)B * Dk;
    size_t o_xhi   = alloc(XS * 2);               // x_hi  -> later xm_bf16
    size_t o_xlo   = alloc(XS * 2);               // x_lo  -> later e1_acc | e1_bf16 | e2_acc
    size_t o_bufh  = alloc((size_t)B * H * 4);
    size_t o_hhi   = alloc((size_t)B * H * 2);
    size_t o_hlo   = alloc((size_t)B * H * 2);
    size_t o_e2b   = alloc((size_t)B * H * 2);
    size_t o_e3a   = alloc((size_t)B * H * 4);
    size_t o_e3b   = alloc((size_t)B * H * 2);
    size_t o_e4    = alloc((size_t)B * H * 4);
    size_t o_z     = alloc((size_t)B * Z * 4);
    size_t o_dbf   = alloc((size_t)B * 2 * H * 2);
    size_t o_csum  = alloc(512 * 4);
    size_t o_csq   = alloc(512 * 4);
    size_t o_w1th  = alloc((size_t)H * Dk * 2);
    size_t o_w1tl  = alloc((size_t)H * Dk * 2);
    size_t o_w2th  = alloc((size_t)Dn * H * 2);
    size_t o_w2tl  = alloc((size_t)Dn * H * 2);
    size_t o_e1wt  = alloc((size_t)(2 * H) * Dk * 2);
    size_t o_e2wt  = alloc((size_t)H * (2 * H) * 2);
    size_t o_e3wt  = alloc((size_t)H * H * 2);
    size_t o_e4wt  = alloc((size_t)H * H * 2);
    size_t o_d2wt  = alloc((size_t)Dn * (2 * H) * 2);

    short* x_hi  = (short*)(base + o_xhi);
    short* x_lo  = (short*)(base + o_xlo);
    short* xm_bf = (short*)(base + o_xhi);
    float* e1_acc = (float*)(base + o_xlo);
    short* e1_bf  = (short*)(base + o_xlo + (size_t)B * 2 * H * 4);
    float* e2_acc = (float*)(base + o_xlo + (size_t)B * 2 * H * 4 + (size_t)B * 2 * H * 2);
    float* buf_h = (float*)(base + o_bufh);
    short* h_hi  = (short*)(base + o_hhi);
    short* h_lo  = (short*)(base + o_hlo);
    short* e2_bf = (short*)(base + o_e2b);
    float* e3_acc = (float*)(base + o_e3a);
    short* e3_bf = (short*)(base + o_e3b);
    float* e4    = (float*)(base + o_e4);
    float* zbuf  = (float*)(base + o_z);
    short* d_bf  = (short*)(base + o_dbf);
    float* csum  = (float*)(base + o_csum);
    float* csq   = (float*)(base + o_csq);
    short* w1t_h = (short*)(base + o_w1th);
    short* w1t_l = (short*)(base + o_w1tl);
    short* w2t_h = (short*)(base + o_w2th);
    short* w2t_l = (short*)(base + o_w2tl);
    short* e1wt  = (short*)(base + o_e1wt);
    short* e2wt  = (short*)(base + o_e2wt);
    short* e3wt  = (short*)(base + o_e3wt);
    short* e4wt  = (short*)(base + o_e4wt);
    short* d2wt  = (short*)(base + o_d2wt);

    dim3 tb(32, 32);

    // ---- packs ----
    pack_a_split<<<dim3((Dk / 4 + 255) / 256, B), 256, 0, stream>>>(x, x_hi, x_lo, D, Dk);
    pack_bt<1><<<dim3(Dk / 32, H / 32), tb, 0, stream>>>(wc_w1, w1t_h, w1t_l, D, H, Dk, H);
    pack_bt<1><<<dim3(H / 32, Dn / 32), tb, 0, stream>>>(wc_w2, w2t_h, w2t_l, H, D, H, Dn);
    pack_bt<0><<<dim3(Dk / 32, 2 * H / 32), tb, 0, stream>>>(enc_w1, e1wt, nullptr, D, 2 * H, Dk, 2 * H);
    pack_bt<0><<<dim3(2 * H / 32, H / 32), tb, 0, stream>>>(enc_w2, e2wt, nullptr, 2 * H, H, 2 * H, H);
    pack_bt<0><<<dim3(H / 32, H / 32), tb, 0, stream>>>(enc_w3, e3wt, nullptr, H, H, H, H);
    pack_bt<0><<<dim3(H / 32, H / 32), tb, 0, stream>>>(enc_w4, e4wt, nullptr, H, H, H, H);
    pack_bt<0><<<dim3(2 * H / 32, Dn / 32), tb, 0, stream>>>(dec_w2, d2wt, nullptr, 2 * H, D, 2 * H, Dn);

    // ---- weight_creator: h = x@wc_w1 (SPLIT, SK=4, atomic) ----
    zero_kernel<<<(B * H + 255) / 256, 256, 0, stream>>>(buf_h, B * H);
    zero_kernel<<<4, 256, 0, stream>>>(csum, 1024);
    gemm_mfma<1, 0, 0, 1, 0><<<dim3(H / 128, B / 128, 4), 256, 0, stream>>>(
        x_hi, x_lo, w1t_h, w1t_l, nullptr, nullptr, buf_h, nullptr, H, Dk);
    bn_stats_kernel<<<128, 256, 0, stream>>>(buf_h, csum, csq);
    bn_apply_split<<<B * H / 256, 256, 0, stream>>>(buf_h, csum, csq, bn_g, bn_b, h_hi, h_lo);

    // ---- w = h@wc_w2 + b2 + gumbel (SPLIT, SK=1, fused epilogue) ----
    gemm_mfma<1, 0, 1, 0, 0><<<dim3((D + 127) / 128, B / 128, 1), 256, 0, stream>>>(
        h_hi, h_lo, w2t_h, w2t_l, wc_b2, noise, w_buf, nullptr, D, H);

    // ---- continuous top-k + mask -> xm bf16 ----
    topk_xm_kernel<<<B, 256, 0, stream>>>(w_buf, x, xm_bf, D);

    // ---- encoder ----
    zero_kernel<<<(B * 2 * H + 255) / 256, 256, 0, stream>>>(e1_acc, B * 2 * H);
    gemm_mfma<0, 0, 0, 1, 0><<<dim3(2 * H / 128, B / 128, 2), 256, 0, stream>>>(
        xm_bf, nullptr, e1wt, nullptr, nullptr, nullptr, e1_acc, nullptr, 2 * H, Dk);
    bias_act<1><<<(B * 2 * H + 255) / 256, 256, 0, stream>>>(e1_acc, enc_b1, nullptr, e1_bf, 2 * H - 1, B * 2 * H);

    zero_kernel<<<(B * H + 255) / 256, 256, 0, stream>>>(e2_acc, B * H);
    gemm_mfma<0, 0, 0, 1, 0><<<dim3(H / 128, B / 128, 4), 256, 0, stream>>>(
        e1_bf, nullptr, e2wt, nullptr, nullptr, nullptr, e2_acc, nullptr, H, 2 * H);
    bias_act<1><<<(B * H + 255) / 256, 256, 0, stream>>>(e2_acc, enc_b2, nullptr, e2_bf, H - 1, B * H);

    zero_kernel<<<(B * H + 255) / 256, 256, 0, stream>>>(e3_acc, B * H);
    gemm_mfma<0, 0, 0, 1, 0><<<dim3(H / 128, B / 128, 4), 256, 0, stream>>>(
        e2_bf, nullptr, e3wt, nullptr, nullptr, nullptr, e3_acc, nullptr, H, H);
    bias_act<1><<<(B * H + 255) / 256, 256, 0, stream>>>(e3_acc, enc_b3, nullptr, e3_bf, H - 1, B * H);

    zero_kernel<<<(B * H + 255) / 256, 256, 0, stream>>>(e4, B * H);
    gemm_mfma<0, 0, 0, 1, 0><<<dim3(H / 128, B / 128, 4), 256, 0, stream>>>(
        e3_bf, nullptr, e4wt, nullptr, nullptr, nullptr, e4, nullptr, H, H);
    bias_act<0><<<(B * H + 255) / 256, 256, 0, stream>>>(e4, enc_b4, e4, nullptr, H - 1, B * H);

    // ---- latent heads + reparameterize ----
    gemm_f32<0, 0><<<dim3(1, B / 64), 256, 0, stream>>>(e4, mean_w, mean_b, mu_l, nullptr, B, Z, H);
    gemm_f32<0, 0><<<dim3(1, B / 64), 256, 0, stream>>>(e4, lv_w, lv_b, lv_l, nullptr, B, Z, H);
    reparam_kernel<<<(B * Z + 255) / 256, 256, 0, stream>>>(mu_l, lv_l, epsv, zbuf, B * Z);

    // ---- decoder ----
    gemm_f32<2, 1><<<dim3(2 * H / 64, B / 64), 256, 0, stream>>>(zbuf, dec_w1, dec_b1, nullptr, d_bf, B, 2 * H, Z);
    gemm_mfma<0, 3, 0, 0, 0><<<dim3((D + 127) / 128, B / 128, 1), 256, 0, stream>>>(
        d_bf, nullptr, d2wt, nullptr, dec_b2, nullptr, mu_x, nullptr, D, 2 * H);
}

// Round 6
// 1123.484 us; speedup vs baseline: 1.0271x; 1.0271x over previous
//
#include <hip/hip_runtime.h>
#include <math.h>

// ---------------------------------------------------------------------------
// VAE_Gumbel: B=4096, D=5000, H=512, Z=64
// Round 9: revert async16 (R5 regressed: DMA between barriers exposes full
//   load latency). Back to reg staging, now ROTATED software pipeline:
//   prologue-load tile0; loop = {barrier; regs->LDS; barrier; prefetch
//   tile s+1 into regs; ds_read+MFMA}. Prefetch latency hides under the
//   16/48 MFMAs instead of under a bare barrier-wait.
//   topk kernel unchanged from R7 (131 us, verified).
// out = [mu_x (4096x5000), mu_latent (4096x64), logvar_latent (4096x64)]
// ---------------------------------------------------------------------------

typedef __attribute__((ext_vector_type(8))) short bf16x8;
typedef __attribute__((ext_vector_type(4))) float f32x4;
typedef __attribute__((ext_vector_type(2))) float f32x2;

__device__ __forceinline__ short f2bf(float f) {  // RNE
    unsigned u = __builtin_bit_cast(unsigned, f);
    u += 0x7FFFu + ((u >> 16) & 1u);
    return (short)(u >> 16);
}
__device__ __forceinline__ float bf2f(short s) {
    unsigned u = ((unsigned)(unsigned short)s) << 16;
    return __builtin_bit_cast(float, u);
}

__device__ __forceinline__ float wave_max64(float v) {
#pragma unroll
    for (int off = 32; off > 0; off >>= 1) v = fmaxf(v, __shfl_xor(v, off, 64));
    return v;
}
__device__ __forceinline__ float wave_sum64(float v) {
#pragma unroll
    for (int off = 32; off > 0; off >>= 1) v += __shfl_xor(v, off, 64);
    return v;
}
__device__ __forceinline__ int wave_sum64_i(int v) {
#pragma unroll
    for (int off = 32; off > 0; off >>= 1) v += __shfl_xor(v, off, 64);
    return v;
}

// ======================= MFMA GEMM =========================================
// C[M,N] = A[M,Kp] @ Bt[Np,Kp]^T  (A, Bt bf16 row-major, contiguous Kp)
// 128x128 block tile, BK=32, 256 threads (4 waves, each 64x64).
// Rotated software pipeline: prefetch next K-tile into regs before MFMA.
// SPLIT: A/B given as hi+lo bf16 pairs; acc = hi*hi + hi*lo + lo*hi.
// ATOMIC: split-K accumulation via atomicAdd (no bias/act).
// ACT: 0 none, 2 leaky, 3 sigmoid. GUMBEL: +log(-log(noise+1e-30)).
template <int SPLIT, int ACT, int GUMBEL, int ATOMIC, int OUT_BF16>
__global__ __launch_bounds__(256, 2) void gemm_mfma(
    const short* __restrict__ Ah, const short* __restrict__ Al,
    const short* __restrict__ Bth, const short* __restrict__ Btl,
    const float* __restrict__ bias, const float* __restrict__ noise,
    float* __restrict__ Cf, short* __restrict__ Cb, int N, int Kp)
{
    __shared__ short lds[(SPLIT ? 4 : 2) * 4096];  // As | Bs | (Asl | Bsl)
    short* As = lds;
    short* Bs = lds + 4096;

    const int tid = threadIdx.x;
    const int m0 = blockIdx.y << 7;
    const int n0 = blockIdx.x << 7;

    const int steps = Kp >> 5;
    const int per = (steps + gridDim.z - 1) / gridDim.z;
    const int s_begin = blockIdx.z * per;
    const int s_end = min(steps, s_begin + per);

    const int r = tid >> 2;
    const int p = tid & 3;
    const size_t a_off = (size_t)(m0 + r) * Kp + p * 8;
    const size_t b_off = (size_t)(n0 + r) * Kp + p * 8;
    const size_t row64 = (size_t)64 * Kp;
    short* As_d1 = As + tid * 8;
    short* As_d2 = As + (tid + 256) * 8;
    short* Bs_d1 = Bs + tid * 8;
    short* Bs_d2 = Bs + (tid + 256) * 8;

    const int lane = tid & 63;
    const int wid = tid >> 6;
    const int wm = (wid >> 1) << 6;
    const int wn = (wid & 1) << 6;
    const int fr = lane & 15;
    const int quad = lane >> 4;

    f32x4 acc[4][4];
#pragma unroll
    for (int i = 0; i < 4; i++)
#pragma unroll
        for (int j = 0; j < 4; j++)
            acc[i][j] = (f32x4){0.f, 0.f, 0.f, 0.f};

    uint4 a1, a2, b1, b2, a3, a4, b3, b4;
    if (s_begin < s_end) {            // prologue: load first K-tile
        const size_t k0 = (size_t)s_begin << 5;
        a1 = *(const uint4*)(Ah + a_off + k0);
        a2 = *(const uint4*)(Ah + a_off + row64 + k0);
        b1 = *(const uint4*)(Bth + b_off + k0);
        b2 = *(const uint4*)(Bth + b_off + row64 + k0);
        if (SPLIT) {
            a3 = *(const uint4*)(Al + a_off + k0);
            a4 = *(const uint4*)(Al + a_off + row64 + k0);
            b3 = *(const uint4*)(Btl + b_off + k0);
            b4 = *(const uint4*)(Btl + b_off + row64 + k0);
        }
    }

    for (int s = s_begin; s < s_end; s++) {
        __syncthreads();               // prev tile fully consumed
        *(uint4*)As_d1 = a1; *(uint4*)As_d2 = a2;
        *(uint4*)Bs_d1 = b1; *(uint4*)Bs_d2 = b2;
        if (SPLIT) {
            *(uint4*)(As_d1 + 8192) = a3; *(uint4*)(As_d2 + 8192) = a4;
            *(uint4*)(Bs_d1 + 8192) = b3; *(uint4*)(Bs_d2 + 8192) = b4;
        }
        __syncthreads();

        if (s + 1 < s_end) {           // prefetch next tile; hides under MFMA
            const size_t k1 = (size_t)(s + 1) << 5;
            a1 = *(const uint4*)(Ah + a_off + k1);
            a2 = *(const uint4*)(Ah + a_off + row64 + k1);
            b1 = *(const uint4*)(Bth + b_off + k1);
            b2 = *(const uint4*)(Bth + b_off + row64 + k1);
            if (SPLIT) {
                a3 = *(const uint4*)(Al + a_off + k1);
                a4 = *(const uint4*)(Al + a_off + row64 + k1);
                b3 = *(const uint4*)(Btl + b_off + k1);
                b4 = *(const uint4*)(Btl + b_off + row64 + k1);
            }
        }

        bf16x8 af[4], bf[4];
#pragma unroll
        for (int i = 0; i < 4; i++)
            af[i] = *(const bf16x8*)(As + ((wm + i * 16 + fr) << 5) + (quad << 3));
#pragma unroll
        for (int j = 0; j < 4; j++)
            bf[j] = *(const bf16x8*)(Bs + ((wn + j * 16 + fr) << 5) + (quad << 3));
#pragma unroll
        for (int i = 0; i < 4; i++)
#pragma unroll
            for (int j = 0; j < 4; j++)
                acc[i][j] = __builtin_amdgcn_mfma_f32_16x16x32_bf16(af[i], bf[j], acc[i][j], 0, 0, 0);
        if (SPLIT) {
            bf16x8 al[4], bl[4];
#pragma unroll
            for (int i = 0; i < 4; i++)
                al[i] = *(const bf16x8*)(As + 8192 + ((wm + i * 16 + fr) << 5) + (quad << 3));
#pragma unroll
            for (int j = 0; j < 4; j++)
                bl[j] = *(const bf16x8*)(Bs + 8192 + ((wn + j * 16 + fr) << 5) + (quad << 3));
#pragma unroll
            for (int i = 0; i < 4; i++)
#pragma unroll
                for (int j = 0; j < 4; j++) {
                    acc[i][j] = __builtin_amdgcn_mfma_f32_16x16x32_bf16(af[i], bl[j], acc[i][j], 0, 0, 0);
                    acc[i][j] = __builtin_amdgcn_mfma_f32_16x16x32_bf16(al[i], bf[j], acc[i][j], 0, 0, 0);
                }
        }
    }

    // epilogue: D row = quad*4+rr, col = fr (m89/m91-verified layout)
#pragma unroll
    for (int i = 0; i < 4; i++) {
#pragma unroll
        for (int j = 0; j < 4; j++) {
#pragma unroll
            for (int rr = 0; rr < 4; rr++) {
                int gm = m0 + wm + i * 16 + quad * 4 + rr;
                int gn = n0 + wn + j * 16 + fr;
                if (gn < N) {
                    size_t o = (size_t)gm * N + gn;
                    float v = acc[i][j][rr];
                    if (ATOMIC) {
                        atomicAdd(Cf + o, v);
                    } else {
                        v += bias[gn];
                        if (GUMBEL) v += __logf(-__logf(noise[o] + 1e-30f));
                        if (ACT == 2) v = v > 0.f ? v : 0.01f * v;
                        if (ACT == 3) v = 1.f / (1.f + __expf(-v));
                        if (OUT_BF16) Cb[o] = f2bf(v); else Cf[o] = v;
                    }
                }
            }
        }
    }
}

// ======================= fp32 vector GEMM (small shapes) ===================
#define TILE 64
#define GBK  16
#define LDP  (TILE + 4)

template <int ACT, int OB>
__global__ __launch_bounds__(256) void gemm_f32(
    const float* __restrict__ A, const float* __restrict__ B,
    const float* __restrict__ bias, float* __restrict__ Cf, short* __restrict__ Cb,
    int M, int N, int K)
{
    __shared__ float As[GBK][LDP];
    __shared__ float Bs[GBK][LDP];
    const int tid = threadIdx.x;
    const int tx = tid & 15;
    const int ty = tid >> 4;
    const int m0 = blockIdx.y * TILE;
    const int n0 = blockIdx.x * TILE;

    float acc[4][4] = {};

    for (int k0 = 0; k0 < K; k0 += GBK) {
#pragma unroll
        for (int t = 0; t < 4; t++) {
            int idx = tid + t * 256;
            int ml = idx >> 4, kk = idx & 15;
            int gm = m0 + ml, gk = k0 + kk;
            As[kk][ml] = (gm < M && gk < K) ? A[(size_t)gm * K + gk] : 0.0f;
        }
#pragma unroll
        for (int t = 0; t < 4; t++) {
            int idx = tid + t * 256;
            int kb = idx >> 6, nl = idx & 63;
            int gk = k0 + kb, gn = n0 + nl;
            Bs[kb][nl] = (gk < K && gn < N) ? B[(size_t)gk * N + gn] : 0.0f;
        }
        __syncthreads();
#pragma unroll
        for (int kk = 0; kk < GBK; kk++) {
            float4 av = *(const float4*)&As[kk][ty * 4];
            float4 bv = *(const float4*)&Bs[kk][tx * 4];
            float a_[4] = {av.x, av.y, av.z, av.w};
            float b_[4] = {bv.x, bv.y, bv.z, bv.w};
#pragma unroll
            for (int i = 0; i < 4; i++)
#pragma unroll
                for (int j = 0; j < 4; j++)
                    acc[i][j] = fmaf(a_[i], b_[j], acc[i][j]);
        }
        __syncthreads();
    }

#pragma unroll
    for (int i = 0; i < 4; i++) {
        int gm = m0 + ty * 4 + i;
        if (gm >= M) continue;
#pragma unroll
        for (int j = 0; j < 4; j++) {
            int gn = n0 + tx * 4 + j;
            if (gn >= N) continue;
            float v = acc[i][j] + bias[gn];
            if (ACT == 2) v = (v > 0.0f) ? v : 0.01f * v;
            if (OB) Cb[(size_t)gm * N + gn] = f2bf(v);
            else    Cf[(size_t)gm * N + gn] = v;
        }
    }
}

// ======================= packs / BN / misc =================================
// A pack with split: fp32 [M,K] -> hi/lo bf16 [M,Kp], 4 elems/thread
__global__ __launch_bounds__(256) void pack_a_split(
    const float* __restrict__ in, short* __restrict__ hi, short* __restrict__ lo,
    int K, int Kp)
{
    int k4 = (blockIdx.x * 256 + threadIdx.x) * 4;
    if (k4 >= Kp) return;
    int m = blockIdx.y;
    float v[4] = {0.f, 0.f, 0.f, 0.f};
    if (k4 + 3 < K) {
        float4 f = *(const float4*)(in + (size_t)m * K + k4);
        v[0] = f.x; v[1] = f.y; v[2] = f.z; v[3] = f.w;
    } else {
#pragma unroll
        for (int j = 0; j < 4; j++)
            if (k4 + j < K) v[j] = in[(size_t)m * K + k4 + j];
    }
    unsigned hp[2], lp[2];
#pragma unroll
    for (int j = 0; j < 2; j++) {
        short h0 = f2bf(v[2 * j]), h1 = f2bf(v[2 * j + 1]);
        short l0 = f2bf(v[2 * j] - bf2f(h0)), l1 = f2bf(v[2 * j + 1] - bf2f(h1));
        hp[j] = (unsigned)(unsigned short)h0 | ((unsigned)(unsigned short)h1 << 16);
        lp[j] = (unsigned)(unsigned short)l0 | ((unsigned)(unsigned short)l1 << 16);
    }
    size_t o = (size_t)m * Kp + k4;
    *(uint2*)(hi + o) = *(uint2*)hp;
    *(uint2*)(lo + o) = *(uint2*)lp;
}

// B^T pack: in fp32 [K,N] -> bf16 [Np,Kp] transposed (zero pad)
template <int SPLITB>
__global__ __launch_bounds__(1024) void pack_bt(
    const float* __restrict__ B, short* __restrict__ bth, short* __restrict__ btl,
    int K, int N, int Kp, int Np)
{
    __shared__ float t[32][33];
    int k0 = blockIdx.x * 32, n0 = blockIdx.y * 32;
    int tx = threadIdx.x, ty = threadIdx.y;
    int gk = k0 + ty, gn = n0 + tx;
    t[ty][tx] = (gk < K && gn < N) ? B[(size_t)gk * N + gn] : 0.f;
    __syncthreads();
    int on = n0 + ty, ok = k0 + tx;
    if (on < Np && ok < Kp) {
        float v = t[tx][ty];
        short h = f2bf(v);
        size_t o = (size_t)on * Kp + ok;
        bth[o] = h;
        if (SPLITB) btl[o] = f2bf(v - bf2f(h));
    }
}

__global__ __launch_bounds__(256) void bn_stats_kernel(
    const float* __restrict__ h, float* __restrict__ csum, float* __restrict__ csq)
{
    int c = threadIdx.x;
    int r0 = blockIdx.x * 32;
    float s0 = 0, q0 = 0, s1 = 0, q1 = 0;
    for (int r = 0; r < 32; r++) {
        const float* row = h + (size_t)(r0 + r) * 512;
        float a = row[c], b = row[c + 256];
        s0 += a; q0 = fmaf(a, a, q0);
        s1 += b; q1 = fmaf(b, b, q1);
    }
    atomicAdd(&csum[c], s0);       atomicAdd(&csq[c], q0);
    atomicAdd(&csum[c + 256], s1); atomicAdd(&csq[c + 256], q1);
}

__global__ __launch_bounds__(256) void bn_apply_split(
    const float* __restrict__ h, const float* __restrict__ csum, const float* __restrict__ csq,
    const float* __restrict__ g, const float* __restrict__ b,
    short* __restrict__ hh, short* __restrict__ hl)
{
    int idx = blockIdx.x * 256 + threadIdx.x;
    int c = idx & 511;
    float mean = csum[c] * (1.0f / 4096.0f);
    float var  = csq[c] * (1.0f / 4096.0f) - mean * mean;
    float inv  = rsqrtf(var + 1e-5f);
    float v = (h[idx] - mean) * inv * g[c] + b[c];
    v = fmaxf(v, 0.0f);
    short hi = f2bf(v);
    hh[idx] = hi;
    hl[idx] = f2bf(v - bf2f(hi));
}

template <int OB>
__global__ __launch_bounds__(256) void bias_act(
    const float* __restrict__ in, const float* __restrict__ bias,
    float* __restrict__ outf, short* __restrict__ outb, int mask, int total)
{
    int i = blockIdx.x * 256 + threadIdx.x;
    if (i < total) {
        float v = in[i] + bias[i & mask];
        v = v > 0.f ? v : 0.01f * v;
        if (OB) outb[i] = f2bf(v); else outf[i] = v;
    }
}

__global__ void zero_kernel(float* p, int n) {
    int i = blockIdx.x * 256 + threadIdx.x;
    if (i < n) p[i] = 0.0f;
}

// ---- continuous top-k (K=50, T=0.1), active-set compaction ----------------
// (unchanged from R7: 131 us, verified)
#define CMAX 2048

__global__ __launch_bounds__(256) void topk_xm_kernel(
    const float* __restrict__ wsrc, const float* __restrict__ x,
    short* __restrict__ xm, int N)   // N even, N <= 5024
{
    __shared__ float tc[CMAX];
    __shared__ unsigned short ic[CMAX];
    __shared__ float redmx[4];
    __shared__ float redsum[4];
    __shared__ int   redcnt[4];
    __shared__ float redsi[4];
    __shared__ float red[2][4];
    __shared__ int cnt_sh;

    const int row = blockIdx.x;
    const int tid = threadIdx.x;
    const int lane = tid & 63;
    const int wid = tid >> 6;
    const float* wr = wsrc + (size_t)row * N;
    const float* xr = x + (size_t)row * N;
    short* xmr = xm + (size_t)row * 5024;

    if (tid == 0) cnt_sh = 0;

    // ---- load w (pairs), block max C ----
    f32x2 w[10];
    float lm = -3.0e38f;
#pragma unroll
    for (int i = 0; i < 10; i++) {
        int e0 = (tid + (i << 8)) << 1;
        f32x2 v;
        if (e0 < N) v = *(const f32x2*)(wr + e0);
        else        v = (f32x2){-3.0e38f, -3.0e38f};
        w[i] = v;
        lm = fmaxf(lm, fmaxf(v[0], v[1]));
    }
    lm = wave_max64(lm);
    if (lane == 0) redmx[wid] = lm;
    __syncthreads();
    const float C = fmaxf(fmaxf(redmx[0], redmx[1]), fmaxf(redmx[2], redmx[3]));

    // ---- t init + s0 ----
    f32x2 t2[10];
    float ls = 0.0f;
#pragma unroll
    for (int i = 0; i < 10; i++) {
        int e0 = (tid + (i << 8)) << 1;
        f32x2 ti;
        if (e0 < N) {
            ti[0] = __expf((w[i][0] - C) * 10.0f);
            ti[1] = __expf((w[i][1] - C) * 10.0f);
        } else {
            ti = (f32x2){0.f, 0.f};
        }
        t2[i] = ti;
        ls += ti[0] + ti[1];
    }
    ls = wave_sum64(ls);
    if (lane == 0) redsum[wid] = ls;
    __syncthreads();
    const float s0 = redsum[0] + redsum[1] + redsum[2] + redsum[3];

    // ---- adaptive threshold: counts at th1, th2 (packed int reduce) ----
    const float th1 = 1e-8f * s0, th2 = 1e-7f * s0;
    int cpk = 0;
#pragma unroll
    for (int i = 0; i < 10; i++) {
#pragma unroll
        for (int h = 0; h < 2; h++) {
            float tv = t2[i][h];
            cpk += (tv > th1 ? 1 : 0) + (tv > th2 ? (1 << 16) : 0);
        }
    }
    cpk = wave_sum64_i(cpk);
    if (lane == 0) redcnt[wid] = cpk;
    __syncthreads();
    int ctot = redcnt[0] + redcnt[1] + redcnt[2] + redcnt[3];
    const int c1 = ctot & 0xFFFF;
    const float TH = (c1 <= CMAX) ? th1 : th2;

    // ---- s_inact = sum of inactive t ----
    float si = 0.0f;
#pragma unroll
    for (int i = 0; i < 10; i++) {
#pragma unroll
        for (int h = 0; h < 2; h++) {
            float tv = t2[i][h];
            si += (tv > TH) ? 0.0f : tv;
        }
    }
    si = wave_sum64(si);
    if (lane == 0) redsi[wid] = si;
    __syncthreads();
    const float s_inact = redsi[0] + redsi[1] + redsi[2] + redsi[3];

    // ---- compaction: ballot + mbcnt prefix within wave, LDS atomic base ----
#pragma unroll
    for (int i = 0; i < 10; i++) {
#pragma unroll
        for (int h = 0; h < 2; h++) {
            float tv = t2[i][h];
            bool act = tv > TH;
            unsigned long long mk = __ballot(act);
            int wb = 0;
            if (lane == 0) wb = atomicAdd(&cnt_sh, (int)__popcll(mk));
            wb = __shfl(wb, 0);
            if (act) {
                int pos = wb + (int)__builtin_amdgcn_mbcnt_hi(
                    (unsigned)(mk >> 32),
                    __builtin_amdgcn_mbcnt_lo((unsigned)mk, 0u));
                if (pos < CMAX) {
                    tc[pos] = tv;
                    ic[pos] = (unsigned short)(((tid + (i << 8)) << 1) + h);
                }
            }
        }
    }
    __syncthreads();
    const int cnt = min(cnt_sh, CMAX);

    // ---- gather candidates into 8 register slots (4 pairs) ----
    f32x2 tr[4], sr[4];
#pragma unroll
    for (int kk = 0; kk < 4; kk++) {
        int s_lo = tid + ((kk * 2) << 8);
        int s_hi = tid + ((kk * 2 + 1) << 8);
        tr[kk][0] = (s_lo < cnt) ? tc[s_lo] : 0.0f;
        tr[kk][1] = (s_hi < cnt) ? tc[s_hi] : 0.0f;
        sr[kk] = (f32x2){0.f, 0.f};
    }

    // ---- 50-iteration recurrence on the active set ----
    float s = s0;
    for (int it = 0; it < 50; it++) {
        const float rs = 1.0f / s;
        const f32x2 rs2 = {rs, rs};
        f32x2 nls2 = {0.f, 0.f};
#pragma unroll
        for (int kk = 0; kk < 4; kk++) {
            f32x2 ti = tr[kk];
            f32x2 oh = ti * rs2;
            sr[kk] += oh;
            f32x2 m = (f32x2){1.f, 1.f} - oh;
            f32x2 m2 = m * m;
            f32x2 m4 = m2 * m2;
            f32x2 m8 = m4 * m4;
            ti *= m8 * m2;          // * (1-oh)^10
            tr[kk] = ti;
            nls2 += ti;
        }
        float nls = wave_sum64(nls2[0] + nls2[1]);
        int buf = (it + 1) & 1;
        if (lane == 0) red[buf][wid] = nls;
        __syncthreads();
        s = fmaxf(red[buf][0] + red[buf][1] + red[buf][2] + red[buf][3] + s_inact,
                  1e-30f);
    }

    // ---- zero-fill xm row (incl. pad), then scatter candidates ----
#pragma unroll
    for (int i = 0; i < 10; i++) {
        int e0 = (tid + (i << 8)) << 1;
        if (e0 < 5024) *(unsigned*)(xmr + e0) = 0u;
    }
    __syncthreads();
#pragma unroll
    for (int k = 0; k < 8; k++) {
        int slot = tid + (k << 8);
        if (slot < cnt) {
            int idx = ic[slot];
            float sv = sr[k >> 1][k & 1];
            xmr[idx] = f2bf(xr[idx] * sv);
        }
    }
}

__global__ void reparam_kernel(const float* __restrict__ mu, const float* __restrict__ lv,
                               const float* __restrict__ eps, float* __restrict__ z, int n)
{
    int i = blockIdx.x * 256 + threadIdx.x;
    if (i < n) z[i] = fmaf(eps[i], expf(0.5f * lv[i]), mu[i]);
}

// ---------------------------------------------------------------------------
extern "C" void kernel_launch(void* const* d_in, const int* in_sizes, int n_in,
                              void* d_out, int out_size, void* d_ws, size_t ws_size,
                              hipStream_t stream)
{
    const float* x      = (const float*)d_in[0];
    const float* noise  = (const float*)d_in[1];
    const float* epsv   = (const float*)d_in[2];
    const float* wc_w1  = (const float*)d_in[3];
    const float* bn_g   = (const float*)d_in[5];
    const float* bn_b   = (const float*)d_in[6];
    const float* wc_w2  = (const float*)d_in[7];
    const float* wc_b2  = (const float*)d_in[8];
    const float* enc_w1 = (const float*)d_in[9];
    const float* enc_b1 = (const float*)d_in[10];
    const float* enc_w2 = (const float*)d_in[11];
    const float* enc_b2 = (const float*)d_in[12];
    const float* enc_w3 = (const float*)d_in[13];
    const float* enc_b3 = (const float*)d_in[14];
    const float* enc_w4 = (const float*)d_in[15];
    const float* enc_b4 = (const float*)d_in[16];
    const float* mean_w = (const float*)d_in[17];
    const float* mean_b = (const float*)d_in[18];
    const float* lv_w   = (const float*)d_in[19];
    const float* lv_b   = (const float*)d_in[20];
    const float* dec_w1 = (const float*)d_in[21];
    const float* dec_b1 = (const float*)d_in[22];
    const float* dec_w2 = (const float*)d_in[23];
    const float* dec_b2 = (const float*)d_in[24];

    const int B = 4096, D = 5000, H = 512, Z = 64;
    const int Dk = 5024;   // D padded to 32 (K pad)
    const int Dn = 5120;   // D padded to 128 (N pad for Bt rows)

    float* out  = (float*)d_out;
    float* mu_x = out;                        // also holds w until topk
    float* mu_l = out + (size_t)B * D;
    float* lv_l = mu_l + (size_t)B * Z;
    float* w_buf = mu_x;

    char* base = (char*)d_ws;
    size_t off = 0;
    auto alloc = [&](size_t bytes) { size_t r = off; off += (bytes + 255) & ~(size_t)255; return r; };
    const size_t XS = (size_t)B * Dk;
    size_t o_xhi   = alloc(XS * 2);               // x_hi  -> later xm_bf16
    size_t o_xlo   = alloc(XS * 2);               // x_lo  -> later e1_acc | e1_bf16 | e2_acc
    size_t o_bufh  = alloc((size_t)B * H * 4);
    size_t o_hhi   = alloc((size_t)B * H * 2);
    size_t o_hlo   = alloc((size_t)B * H * 2);
    size_t o_e2b   = alloc((size_t)B * H * 2);
    size_t o_e3a   = alloc((size_t)B * H * 4);
    size_t o_e3b   = alloc((size_t)B * H * 2);
    size_t o_e4    = alloc((size_t)B * H * 4);
    size_t o_z     = alloc((size_t)B * Z * 4);
    size_t o_dbf   = alloc((size_t)B * 2 * H * 2);
    size_t o_csum  = alloc(512 * 4);
    size_t o_csq   = alloc(512 * 4);
    size_t o_w1th  = alloc((size_t)H * Dk * 2);
    size_t o_w1tl  = alloc((size_t)H * Dk * 2);
    size_t o_w2th  = alloc((size_t)Dn * H * 2);
    size_t o_w2tl  = alloc((size_t)Dn * H * 2);
    size_t o_e1wt  = alloc((size_t)(2 * H) * Dk * 2);
    size_t o_e2wt  = alloc((size_t)H * (2 * H) * 2);
    size_t o_e3wt  = alloc((size_t)H * H * 2);
    size_t o_e4wt  = alloc((size_t)H * H * 2);
    size_t o_d2wt  = alloc((size_t)Dn * (2 * H) * 2);

    short* x_hi  = (short*)(base + o_xhi);
    short* x_lo  = (short*)(base + o_xlo);
    short* xm_bf = (short*)(base + o_xhi);
    float* e1_acc = (float*)(base + o_xlo);
    short* e1_bf  = (short*)(base + o_xlo + (size_t)B * 2 * H * 4);
    float* e2_acc = (float*)(base + o_xlo + (size_t)B * 2 * H * 4 + (size_t)B * 2 * H * 2);
    float* buf_h = (float*)(base + o_bufh);
    short* h_hi  = (short*)(base + o_hhi);
    short* h_lo  = (short*)(base + o_hlo);
    short* e2_bf = (short*)(base + o_e2b);
    float* e3_acc = (float*)(base + o_e3a);
    short* e3_bf = (short*)(base + o_e3b);
    float* e4    = (float*)(base + o_e4);
    float* zbuf  = (float*)(base + o_z);
    short* d_bf  = (short*)(base + o_dbf);
    float* csum  = (float*)(base + o_csum);
    float* csq   = (float*)(base + o_csq);
    short* w1t_h = (short*)(base + o_w1th);
    short* w1t_l = (short*)(base + o_w1tl);
    short* w2t_h = (short*)(base + o_w2th);
    short* w2t_l = (short*)(base + o_w2tl);
    short* e1wt  = (short*)(base + o_e1wt);
    short* e2wt  = (short*)(base + o_e2wt);
    short* e3wt  = (short*)(base + o_e3wt);
    short* e4wt  = (short*)(base + o_e4wt);
    short* d2wt  = (short*)(base + o_d2wt);

    dim3 tb(32, 32);

    // ---- packs ----
    pack_a_split<<<dim3((Dk / 4 + 255) / 256, B), 256, 0, stream>>>(x, x_hi, x_lo, D, Dk);
    pack_bt<1><<<dim3(Dk / 32, H / 32), tb, 0, stream>>>(wc_w1, w1t_h, w1t_l, D, H, Dk, H);
    pack_bt<1><<<dim3(H / 32, Dn / 32), tb, 0, stream>>>(wc_w2, w2t_h, w2t_l, H, D, H, Dn);
    pack_bt<0><<<dim3(Dk / 32, 2 * H / 32), tb, 0, stream>>>(enc_w1, e1wt, nullptr, D, 2 * H, Dk, 2 * H);
    pack_bt<0><<<dim3(2 * H / 32, H / 32), tb, 0, stream>>>(enc_w2, e2wt, nullptr, 2 * H, H, 2 * H, H);
    pack_bt<0><<<dim3(H / 32, H / 32), tb, 0, stream>>>(enc_w3, e3wt, nullptr, H, H, H, H);
    pack_bt<0><<<dim3(H / 32, H / 32), tb, 0, stream>>>(enc_w4, e4wt, nullptr, H, H, H, H);
    pack_bt<0><<<dim3(2 * H / 32, Dn / 32), tb, 0, stream>>>(dec_w2, d2wt, nullptr, 2 * H, D, 2 * H, Dn);

    // ---- weight_creator: h = x@wc_w1 (SPLIT, SK=4, atomic) ----
    zero_kernel<<<(B * H + 255) / 256, 256, 0, stream>>>(buf_h, B * H);
    zero_kernel<<<4, 256, 0, stream>>>(csum, 1024);
    gemm_mfma<1, 0, 0, 1, 0><<<dim3(H / 128, B / 128, 4), 256, 0, stream>>>(
        x_hi, x_lo, w1t_h, w1t_l, nullptr, nullptr, buf_h, nullptr, H, Dk);
    bn_stats_kernel<<<128, 256, 0, stream>>>(buf_h, csum, csq);
    bn_apply_split<<<B * H / 256, 256, 0, stream>>>(buf_h, csum, csq, bn_g, bn_b, h_hi, h_lo);

    // ---- w = h@wc_w2 + b2 + gumbel (SPLIT, SK=1, fused epilogue) ----
    gemm_mfma<1, 0, 1, 0, 0><<<dim3((D + 127) / 128, B / 128, 1), 256, 0, stream>>>(
        h_hi, h_lo, w2t_h, w2t_l, wc_b2, noise, w_buf, nullptr, D, H);

    // ---- continuous top-k + mask -> xm bf16 ----
    topk_xm_kernel<<<B, 256, 0, stream>>>(w_buf, x, xm_bf, D);

    // ---- encoder ----
    zero_kernel<<<(B * 2 * H + 255) / 256, 256, 0, stream>>>(e1_acc, B * 2 * H);
    gemm_mfma<0, 0, 0, 1, 0><<<dim3(2 * H / 128, B / 128, 2), 256, 0, stream>>>(
        xm_bf, nullptr, e1wt, nullptr, nullptr, nullptr, e1_acc, nullptr, 2 * H, Dk);
    bias_act<1><<<(B * 2 * H + 255) / 256, 256, 0, stream>>>(e1_acc, enc_b1, nullptr, e1_bf, 2 * H - 1, B * 2 * H);

    zero_kernel<<<(B * H + 255) / 256, 256, 0, stream>>>(e2_acc, B * H);
    gemm_mfma<0, 0, 0, 1, 0><<<dim3(H / 128, B / 128, 4), 256, 0, stream>>>(
        e1_bf, nullptr, e2wt, nullptr, nullptr, nullptr, e2_acc, nullptr, H, 2 * H);
    bias_act<1><<<(B * H + 255) / 256, 256, 0, stream>>>(e2_acc, enc_b2, nullptr, e2_bf, H - 1, B * H);

    zero_kernel<<<(B * H + 255) / 256, 256, 0, stream>>>(e3_acc, B * H);
    gemm_mfma<0, 0, 0, 1, 0><<<dim3(H / 128, B / 128, 4), 256, 0, stream>>>(
        e2_bf, nullptr, e3wt, nullptr, nullptr, nullptr, e3_acc, nullptr, H, H);
    bias_act<1><<<(B * H + 255) / 256, 256, 0, stream>>>(e3_acc, enc_b3, nullptr, e3_bf, H - 1, B * H);

    zero_kernel<<<(B * H + 255) / 256, 256, 0, stream>>>(e4, B * H);
    gemm_mfma<0, 0, 0, 1, 0><<<dim3(H / 128, B / 128, 4), 256, 0, stream>>>(
        e3_bf, nullptr, e4wt, nullptr, nullptr, nullptr, e4, nullptr, H, H);
    bias_act<0><<<(B * H + 255) / 256, 256, 0, stream>>>(e4, enc_b4, e4, nullptr, H - 1, B * H);

    // ---- latent heads + reparameterize ----
    gemm_f32<0, 0><<<dim3(1, B / 64), 256, 0, stream>>>(e4, mean_w, mean_b, mu_l, nullptr, B, Z, H);
    gemm_f32<0, 0><<<dim3(1, B / 64), 256, 0, stream>>>(e4, lv_w, lv_b, lv_l, nullptr, B, Z, H);
    reparam_kernel<<<(B * Z + 255) / 256, 256, 0, stream>>>(mu_l, lv_l, epsv, zbuf, B * Z);

    // ---- decoder ----
    gemm_f32<2, 1><<<dim3(2 * H / 64, B / 64), 256, 0, stream>>>(zbuf, dec_w1, dec_b1, nullptr, d_bf, B, 2 * H, Z);
    gemm_mfma<0, 3, 0, 0, 0><<<dim3((D + 127) / 128, B / 128, 1), 256, 0, stream>>>(
        d_bf, nullptr, d2wt, nullptr, dec_b2, nullptr, mu_x, nullptr, D, 2 * H);
}